// Round 1
// baseline (1090.655 us; speedup 1.0000x reference)
//
#include <hip/hip_runtime.h>
#include <hip/hip_bf16.h>
#include <math.h>

#define B_ROWS 512
#define D_DIM  2048
#define E_EXP  8

// ---------------- workspace layout (bytes) ----------------
#define O_CNT    0          // int[8]
#define O_OFFS   64         // int[9]
#define O_ROWS   1024       // int[8*512]
#define O_SLOTE  17408      // int[1024]
#define O_SLOTP  21504      // int[1024]
#define O_GSEL   25600      // float[1024]
#define O_GATES  29696      // float[512*8]
#define O_PROB   46080      // float[512*8]
#define O_H      65536      // float[1024*2048]
#define O_S      (65536 + 8388608)  // float[1024*2048]
#define WS_NEEDED (65536 + 2*8388608)

// ---------------- gating kernel: one block per row ----------------
__global__ __launch_bounds__(256) void gate_kernel(
    const float* __restrict__ x, const float* __restrict__ noise,
    const float* __restrict__ wg, const float* __restrict__ wn,
    float* __restrict__ gates, float* __restrict__ prob, float* __restrict__ gsel,
    int* __restrict__ cnt, int* __restrict__ rows,
    int* __restrict__ slot_e, int* __restrict__ slot_p)
{
    const int b = blockIdx.x, t = threadIdx.x;
    float ag[8], an[8];
    #pragma unroll
    for (int e = 0; e < 8; e++) { ag[e] = 0.f; an[e] = 0.f; }
    const float* xr = x + (size_t)b * D_DIM;
    for (int d = t; d < D_DIM; d += 256) {
        float xv = xr[d];
        const float* g = wg + (size_t)d * 8;
        const float* nn = wn + (size_t)d * 8;
        #pragma unroll
        for (int e = 0; e < 8; e++) {
            ag[e] = fmaf(xv, g[e], ag[e]);
            an[e] = fmaf(xv, nn[e], an[e]);
        }
    }
    #pragma unroll
    for (int off = 32; off >= 1; off >>= 1) {
        #pragma unroll
        for (int e = 0; e < 8; e++) {
            ag[e] += __shfl_down(ag[e], off);
            an[e] += __shfl_down(an[e], off);
        }
    }
    __shared__ float rg_[4][8], rn_[4][8];
    const int wid = t >> 6, lane = t & 63;
    if (lane == 0) {
        #pragma unroll
        for (int e = 0; e < 8; e++) { rg_[wid][e] = ag[e]; rn_[wid][e] = an[e]; }
    }
    __syncthreads();
    if (t == 0) {
        float clean[8], sd[8], lg[8];
        #pragma unroll
        for (int e = 0; e < 8; e++) {
            float c = rg_[0][e] + rg_[1][e] + rg_[2][e] + rg_[3][e];
            float s = rn_[0][e] + rn_[1][e] + rn_[2][e] + rn_[3][e];
            clean[e] = c;
            // softplus(s) = max(s,0) + log1p(exp(-|s|))
            float sp = fmaxf(s, 0.f) + log1pf(expf(-fabsf(s)));
            sd[e] = sp + 0.01f;
            lg[e] = c + noise[b * 8 + e] * sd[e];
        }
        // top-3 (ties -> lower index first, matches lax.top_k)
        int i0 = -1, i1 = -1, i2 = -1;
        float v0 = -3.0e38f, v1 = -3.0e38f, v2 = -3.0e38f;
        #pragma unroll
        for (int e = 0; e < 8; e++) {
            float v = lg[e];
            if (v > v0)      { v2 = v1; i2 = i1; v1 = v0; i1 = i0; v0 = v; i0 = e; }
            else if (v > v1) { v2 = v1; i2 = i1; v1 = v; i1 = e; }
            else if (v > v2) { v2 = v; i2 = e; }
        }
        (void)i2;
        float ex1 = expf(v1 - v0);
        float g0 = 1.f / (1.f + ex1);
        float g1 = ex1 / (1.f + ex1);
        float thr_in = v2, thr_out = v1;
        #pragma unroll
        for (int e = 0; e < 8; e++) {
            float thr = (lg[e] > thr_in) ? thr_in : thr_out;
            float z = (clean[e] - thr) / sd[e];
            prob[b * 8 + e] = 0.5f * erfcf(-z * 0.70710678118654752f);  // ndtr
            gates[b * 8 + e] = (e == i0) ? g0 : ((e == i1) ? g1 : 0.f);
        }
        int p0 = atomicAdd(&cnt[i0], 1);
        rows[i0 * 512 + p0] = b; slot_e[2 * b] = i0; slot_p[2 * b] = p0; gsel[2 * b] = g0;
        int p1 = atomicAdd(&cnt[i1], 1);
        rows[i1 * 512 + p1] = b; slot_e[2 * b + 1] = i1; slot_p[2 * b + 1] = p1; gsel[2 * b + 1] = g1;
    }
}

// ---------------- loss + prefix offsets: single block ----------------
__global__ __launch_bounds__(256) void loss_kernel(
    const float* __restrict__ gates, const float* __restrict__ prob,
    const int* __restrict__ cnt, int* __restrict__ offs, float* __restrict__ loss_out)
{
    const int t = threadIdx.x;
    const int e = t & 7;
    float si = 0.f, sl = 0.f;
    for (int b = (t >> 3); b < 512; b += 32) {
        si += gates[b * 8 + e];
        sl += prob[b * 8 + e];
    }
    __shared__ float ti[256], tl[256];
    ti[t] = si; tl[t] = sl;
    __syncthreads();
    for (int s = 128; s >= 8; s >>= 1) {
        if (t < s) { ti[t] += ti[t + s]; tl[t] += tl[t + s]; }
        __syncthreads();
    }
    if (t == 0) {
        double mi = 0, ml = 0;
        for (int k = 0; k < 8; k++) { mi += ti[k]; ml += tl[k]; }
        mi /= 8.0; ml /= 8.0;
        double vi = 0, vl = 0;
        for (int k = 0; k < 8; k++) {
            double di = ti[k] - mi, dl = tl[k] - ml;
            vi += di * di; vl += dl * dl;
        }
        vi /= 7.0; vl /= 7.0;
        loss_out[0] = (float)((vi / (mi * mi + 1e-10) + vl / (ml * ml + 1e-10)) * 0.01);
        offs[0] = 0;
        for (int k = 0; k < 8; k++) offs[k + 1] = offs[k] + cnt[k];
    }
}

// ---------------- grouped expert GEMM (f32), 64x128 tile ----------------
// which==1: A = x gathered via rows[], out = tanh(A@W1+b1) -> H (compact)
// which==2: A = H (compact, sequential), out = A@W2+b2 -> S
__global__ __launch_bounds__(256, 2) void expert_gemm(
    const float* __restrict__ A, const float* __restrict__ W,
    const float* __restrict__ bias, float* __restrict__ Out,
    const int* __restrict__ cnt, const int* __restrict__ offs,
    const int* __restrict__ rows, int which)
{
    const int e = blockIdx.z;
    const int n = cnt[e];
    const int rt = blockIdx.x;
    if (rt * 64 >= n) return;
    const int ct = blockIdx.y;
    const int base = offs[e];

    __shared__ float XsT[16][68];   // [k][row], padded stride 68
    __shared__ float Wsh[16][132];  // [k][col], padded stride 132

    const int t = threadIdx.x;
    // X staging: each thread loads a float4 of one row
    const int xrow_l = t >> 2;
    const int xq = (t & 3) << 2;
    int asg = rt * 64 + xrow_l;
    int asgc = (asg < n) ? asg : (n - 1);
    int arow;
    if (which == 1) arow = rows[e * 512 + asgc];
    else            arow = base + asgc;
    const float* Aptr = A + (size_t)arow * D_DIM + xq;
    // W staging: wr = t>>4 (k-row), wc = (t&15)*8 (col)
    const int wr = t >> 4;
    const int wc = (t & 15) << 3;
    const float* Wptr = W + (size_t)e * D_DIM * D_DIM + (size_t)wr * D_DIM + ct * 128 + wc;

    float acc[4][8];
    #pragma unroll
    for (int i = 0; i < 4; i++)
        #pragma unroll
        for (int j = 0; j < 8; j++) acc[i][j] = 0.f;

    const int rg = t & 15;   // row group: rows rg*4..rg*4+3
    const int cg = t >> 4;   // col group: cols cg*8..cg*8+7

    for (int k0 = 0; k0 < D_DIM; k0 += 16) {
        float4 xv = *(const float4*)(Aptr + k0);
        float4 w0 = *(const float4*)(Wptr + (size_t)k0 * D_DIM);
        float4 w1 = *(const float4*)(Wptr + (size_t)k0 * D_DIM + 4);
        XsT[xq + 0][xrow_l] = xv.x;
        XsT[xq + 1][xrow_l] = xv.y;
        XsT[xq + 2][xrow_l] = xv.z;
        XsT[xq + 3][xrow_l] = xv.w;
        *(float4*)&Wsh[wr][wc]     = w0;
        *(float4*)&Wsh[wr][wc + 4] = w1;
        __syncthreads();
        #pragma unroll
        for (int kk = 0; kk < 16; kk++) {
            float4 a  = *(const float4*)&XsT[kk][rg << 2];
            float4 b0 = *(const float4*)&Wsh[kk][cg << 3];
            float4 b1 = *(const float4*)&Wsh[kk][(cg << 3) + 4];
            float av[4] = {a.x, a.y, a.z, a.w};
            float bv[8] = {b0.x, b0.y, b0.z, b0.w, b1.x, b1.y, b1.z, b1.w};
            #pragma unroll
            for (int i = 0; i < 4; i++)
                #pragma unroll
                for (int j = 0; j < 8; j++)
                    acc[i][j] = fmaf(av[i], bv[j], acc[i][j]);
        }
        __syncthreads();
    }

    const float* brow = bias + (size_t)e * D_DIM + ct * 128 + (cg << 3);
    float bb[8];
    #pragma unroll
    for (int j = 0; j < 8; j++) bb[j] = brow[j];
    #pragma unroll
    for (int i = 0; i < 4; i++) {
        int oasg = rt * 64 + (rg << 2) + i;
        if (oasg < n) {
            float* orow = Out + (size_t)(base + oasg) * D_DIM + ct * 128 + (cg << 3);
            float vv[8];
            #pragma unroll
            for (int j = 0; j < 8; j++) {
                float v = acc[i][j] + bb[j];
                vv[j] = (which == 1) ? tanhf(v) : v;
            }
            *(float4*)&orow[0] = make_float4(vv[0], vv[1], vv[2], vv[3]);
            *(float4*)&orow[4] = make_float4(vv[4], vv[5], vv[6], vv[7]);
        }
    }
}

// ---------------- softmax + combine: one block per output row ----------------
__global__ __launch_bounds__(256) void combine_kernel(
    const float* __restrict__ S, const float* __restrict__ x,
    const int* __restrict__ offs, const int* __restrict__ slot_e,
    const int* __restrict__ slot_p, const float* __restrict__ gsel,
    float* __restrict__ y)
{
    const int b = blockIdx.x, t = threadIdx.x;
    const int e0 = slot_e[2 * b], e1 = slot_e[2 * b + 1];
    const float* S0 = S + (size_t)(offs[e0] + slot_p[2 * b]) * D_DIM;
    const float* S1 = S + (size_t)(offs[e1] + slot_p[2 * b + 1]) * D_DIM;
    const float g0 = gsel[2 * b], g1 = gsel[2 * b + 1];
    __shared__ float sm[2][4];
    const int wid = t >> 6, lane = t & 63;

    float m0 = -3.0e38f, m1 = -3.0e38f;
    for (int d = t; d < D_DIM; d += 256) {
        m0 = fmaxf(m0, S0[d]);
        m1 = fmaxf(m1, S1[d]);
    }
    #pragma unroll
    for (int off = 32; off >= 1; off >>= 1) {
        m0 = fmaxf(m0, __shfl_down(m0, off));
        m1 = fmaxf(m1, __shfl_down(m1, off));
    }
    if (lane == 0) { sm[0][wid] = m0; sm[1][wid] = m1; }
    __syncthreads();
    m0 = fmaxf(fmaxf(sm[0][0], sm[0][1]), fmaxf(sm[0][2], sm[0][3]));
    m1 = fmaxf(fmaxf(sm[1][0], sm[1][1]), fmaxf(sm[1][2], sm[1][3]));
    __syncthreads();

    float s0 = 0.f, s1 = 0.f;
    for (int d = t; d < D_DIM; d += 256) {
        s0 += expf(S0[d] - m0);
        s1 += expf(S1[d] - m1);
    }
    #pragma unroll
    for (int off = 32; off >= 1; off >>= 1) {
        s0 += __shfl_down(s0, off);
        s1 += __shfl_down(s1, off);
    }
    if (lane == 0) { sm[0][wid] = s0; sm[1][wid] = s1; }
    __syncthreads();
    s0 = sm[0][0] + sm[0][1] + sm[0][2] + sm[0][3];
    s1 = sm[1][0] + sm[1][1] + sm[1][2] + sm[1][3];
    const float inv0 = 1.f / s0, inv1 = 1.f / s1;

    for (int d = t; d < D_DIM; d += 256) {
        float a0 = expf(S0[d] - m0) * inv0;
        float a1 = expf(S1[d] - m1) * inv1;
        float xv = x[(size_t)b * D_DIM + d];
        float c = g0 * expf(a0 * xv) + g1 * expf(a1 * xv);
        if (c == 0.f) c = 2.220446049250313e-16f;
        y[(size_t)b * D_DIM + d] = logf(c);
    }
}

extern "C" void kernel_launch(void* const* d_in, const int* in_sizes, int n_in,
                              void* d_out, int out_size, void* d_ws, size_t ws_size,
                              hipStream_t stream) {
    const float* x       = (const float*)d_in[0];
    const float* noise   = (const float*)d_in[1];
    const float* w_gate  = (const float*)d_in[2];
    const float* w_noise = (const float*)d_in[3];
    const float* W1      = (const float*)d_in[4];
    const float* b1      = (const float*)d_in[5];
    const float* W2      = (const float*)d_in[6];
    const float* b2      = (const float*)d_in[7];
    float* out = (float*)d_out;
    char* ws = (char*)d_ws;
    if (ws_size < (size_t)WS_NEEDED) return;  // visible failure rather than corruption

    int*   cnt    = (int*)(ws + O_CNT);
    int*   offs   = (int*)(ws + O_OFFS);
    int*   rows   = (int*)(ws + O_ROWS);
    int*   slot_e = (int*)(ws + O_SLOTE);
    int*   slot_p = (int*)(ws + O_SLOTP);
    float* gsel   = (float*)(ws + O_GSEL);
    float* gates  = (float*)(ws + O_GATES);
    float* prob   = (float*)(ws + O_PROB);
    float* H      = (float*)(ws + O_H);
    float* S      = (float*)(ws + O_S);

    hipMemsetAsync(cnt, 0, 8 * sizeof(int), stream);
    gate_kernel<<<512, 256, 0, stream>>>(x, noise, w_gate, w_noise,
                                         gates, prob, gsel, cnt, rows, slot_e, slot_p);
    loss_kernel<<<1, 256, 0, stream>>>(gates, prob, cnt, offs, out + (size_t)B_ROWS * D_DIM);
    expert_gemm<<<dim3(8, 16, 8), 256, 0, stream>>>(x, W1, b1, H, cnt, offs, rows, 1);
    expert_gemm<<<dim3(8, 16, 8), 256, 0, stream>>>(H, W2, b2, S, cnt, offs, rows, 2);
    combine_kernel<<<512, 256, 0, stream>>>(S, x, offs, slot_e, slot_p, gsel, out);
}

// Round 3
// 545.036 us; speedup vs baseline: 2.0011x; 2.0011x over previous
//
#include <hip/hip_runtime.h>
#include <hip/hip_bf16.h>
#include <math.h>

#define B_ROWS 512
#define D_DIM  2048
#define E_EXP  8
#define BK 64
#define MT 64
#define NT 64
#define KPAD 72

typedef _Float16 half8_t  __attribute__((ext_vector_type(8)));
typedef _Float16 half4_t  __attribute__((ext_vector_type(4)));
typedef float    floatx16 __attribute__((ext_vector_type(16)));

// ---------------- workspace layout (bytes) ----------------
#define O_CNT    0          // int[8]
#define O_OFFS   64         // int[9]
#define O_ROWS   1024       // int[8*512]
#define O_SLOTE  17408      // int[1024]
#define O_SLOTP  21504      // int[1024]
#define O_GSEL   25600      // float[1024]
#define O_GATES  29696      // float[512*8]
#define O_PROB   46080      // float[512*8]
#define O_H      65536      // _Float16[1024*2048]  (4 MB)
#define O_S      (65536 + 4194304)  // float[1024*2048] (8 MB)
#define WS_NEEDED (65536 + 4194304 + 8388608)

// ---------------- gating kernel: one block per row ----------------
__global__ __launch_bounds__(256) void gate_kernel(
    const float* __restrict__ x, const float* __restrict__ noise,
    const float* __restrict__ wg, const float* __restrict__ wn,
    float* __restrict__ gates, float* __restrict__ prob, float* __restrict__ gsel,
    int* __restrict__ cnt, int* __restrict__ rows,
    int* __restrict__ slot_e, int* __restrict__ slot_p)
{
    const int b = blockIdx.x, t = threadIdx.x;
    float ag[8], an[8];
    #pragma unroll
    for (int e = 0; e < 8; e++) { ag[e] = 0.f; an[e] = 0.f; }
    const float* xr = x + (size_t)b * D_DIM;
    for (int d = t; d < D_DIM; d += 256) {
        float xv = xr[d];
        const float* g = wg + (size_t)d * 8;
        const float* nn = wn + (size_t)d * 8;
        #pragma unroll
        for (int e = 0; e < 8; e++) {
            ag[e] = fmaf(xv, g[e], ag[e]);
            an[e] = fmaf(xv, nn[e], an[e]);
        }
    }
    #pragma unroll
    for (int off = 32; off >= 1; off >>= 1) {
        #pragma unroll
        for (int e = 0; e < 8; e++) {
            ag[e] += __shfl_down(ag[e], off);
            an[e] += __shfl_down(an[e], off);
        }
    }
    __shared__ float rg_[4][8], rn_[4][8];
    const int wid = t >> 6, lane = t & 63;
    if (lane == 0) {
        #pragma unroll
        for (int e = 0; e < 8; e++) { rg_[wid][e] = ag[e]; rn_[wid][e] = an[e]; }
    }
    __syncthreads();
    if (t == 0) {
        float clean[8], sd[8], lg[8];
        #pragma unroll
        for (int e = 0; e < 8; e++) {
            float c = rg_[0][e] + rg_[1][e] + rg_[2][e] + rg_[3][e];
            float s = rn_[0][e] + rn_[1][e] + rn_[2][e] + rn_[3][e];
            clean[e] = c;
            float sp = fmaxf(s, 0.f) + log1pf(expf(-fabsf(s)));
            sd[e] = sp + 0.01f;
            lg[e] = c + noise[b * 8 + e] * sd[e];
        }
        int i0 = -1, i1 = -1, i2 = -1;
        float v0 = -3.0e38f, v1 = -3.0e38f, v2 = -3.0e38f;
        #pragma unroll
        for (int e = 0; e < 8; e++) {
            float v = lg[e];
            if (v > v0)      { v2 = v1; i2 = i1; v1 = v0; i1 = i0; v0 = v; i0 = e; }
            else if (v > v1) { v2 = v1; i2 = i1; v1 = v; i1 = e; }
            else if (v > v2) { v2 = v; i2 = e; }
        }
        (void)i2;
        float ex1 = expf(v1 - v0);
        float g0 = 1.f / (1.f + ex1);
        float g1 = ex1 / (1.f + ex1);
        float thr_in = v2, thr_out = v1;
        #pragma unroll
        for (int e = 0; e < 8; e++) {
            float thr = (lg[e] > thr_in) ? thr_in : thr_out;
            float z = (clean[e] - thr) / sd[e];
            prob[b * 8 + e] = 0.5f * erfcf(-z * 0.70710678118654752f);
            gates[b * 8 + e] = (e == i0) ? g0 : ((e == i1) ? g1 : 0.f);
        }
        int p0 = atomicAdd(&cnt[i0], 1);
        rows[i0 * 512 + p0] = b; slot_e[2 * b] = i0; slot_p[2 * b] = p0; gsel[2 * b] = g0;
        int p1 = atomicAdd(&cnt[i1], 1);
        rows[i1 * 512 + p1] = b; slot_e[2 * b + 1] = i1; slot_p[2 * b + 1] = p1; gsel[2 * b + 1] = g1;
    }
}

// ---------------- loss + prefix offsets: single block ----------------
__global__ __launch_bounds__(256) void loss_kernel(
    const float* __restrict__ gates, const float* __restrict__ prob,
    const int* __restrict__ cnt, int* __restrict__ offs, float* __restrict__ loss_out)
{
    const int t = threadIdx.x;
    const int e = t & 7;
    float si = 0.f, sl = 0.f;
    for (int b = (t >> 3); b < 512; b += 32) {
        si += gates[b * 8 + e];
        sl += prob[b * 8 + e];
    }
    __shared__ float ti[256], tl[256];
    ti[t] = si; tl[t] = sl;
    __syncthreads();
    for (int s = 128; s >= 8; s >>= 1) {
        if (t < s) { ti[t] += ti[t + s]; tl[t] += tl[t + s]; }
        __syncthreads();
    }
    if (t == 0) {
        double mi = 0, ml = 0;
        for (int k = 0; k < 8; k++) { mi += ti[k]; ml += tl[k]; }
        mi /= 8.0; ml /= 8.0;
        double vi = 0, vl = 0;
        for (int k = 0; k < 8; k++) {
            double di = ti[k] - mi, dl = tl[k] - ml;
            vi += di * di; vl += dl * dl;
        }
        vi /= 7.0; vl /= 7.0;
        loss_out[0] = (float)((vi / (mi * mi + 1e-10) + vl / (ml * ml + 1e-10)) * 0.01);
        offs[0] = 0;
        for (int k = 0; k < 8; k++) offs[k + 1] = offs[k] + cnt[k];
    }
}

// ---------------- grouped expert GEMM, f16 MFMA 32x32x16 ----------------
// WHICH==1: A = x (f32, gathered via rows[]), out = tanh(A@W1+b1) -> H (f16, compact)
// WHICH==2: A = H (f16, compact),             out = A@W2+b2      -> S (f32, compact)
template<int WHICH>
__global__ __launch_bounds__(256) void expert_gemm_mfma(
    const float* __restrict__ Af, const _Float16* __restrict__ Ah,
    const float* __restrict__ W, const float* __restrict__ bias,
    _Float16* __restrict__ Hout, float* __restrict__ Sout,
    const int* __restrict__ cnt, const int* __restrict__ offs,
    const int* __restrict__ rows)
{
    const int e = blockIdx.z;
    const int n = cnt[e];
    const int rt = blockIdx.x;
    if (rt * MT >= n) return;
    const int ct = blockIdx.y;
    const int base = offs[e];

    __shared__ _Float16 Asl[MT][KPAD];
    __shared__ _Float16 Bsl[NT][KPAD];

    const int t = threadIdx.x;
    // A staging: thread covers row ar, k = ak + 16*j + [0..3]
    const int ar = t >> 2;
    const int ak = (t & 3) * 4;
    int asg = rt * MT + ar; if (asg >= n) asg = n - 1;
    const size_t arow = (WHICH == 1) ? (size_t)rows[e * 512 + asg] : (size_t)(base + asg);
    const float*    Apf = Af + arow * D_DIM;
    const _Float16* Aph = Ah + arow * D_DIM;
    // B staging: thread covers col bn, k = bk + [0..15]
    const int bn = t & 63;
    const int bk = (t >> 6) * 16;
    const float* Wp = W + (size_t)e * D_DIM * D_DIM + (size_t)bk * D_DIM + (size_t)ct * NT + bn;

    // compute map: 4 waves, each one 32x32 quadrant
    const int lane = t & 63;
    const int w = t >> 6;
    const int wr = (w >> 1) * 32;
    const int wc = (w & 1) * 32;
    const int fr = lane & 31;
    const int kg = lane >> 5;

    floatx16 acc;
    #pragma unroll
    for (int i = 0; i < 16; i++) acc[i] = 0.f;

    float4  aregf[4];
    half4_t aregh[4];
    float   breg[16];

    auto do_load = [&](int t0) {
        if constexpr (WHICH == 1) {
            #pragma unroll
            for (int j = 0; j < 4; j++)
                aregf[j] = *(const float4*)(Apf + t0 + ak + 16 * j);
        } else {
            #pragma unroll
            for (int j = 0; j < 4; j++)
                aregh[j] = *(const half4_t*)(Aph + t0 + ak + 16 * j);
        }
        const float* wq = Wp + (size_t)t0 * D_DIM;
        #pragma unroll
        for (int i = 0; i < 16; i++)
            breg[i] = wq[(size_t)i * D_DIM];
    };

    auto do_write = [&]() {
        if constexpr (WHICH == 1) {
            #pragma unroll
            for (int j = 0; j < 4; j++) {
                half4_t h;
                h[0] = (_Float16)aregf[j].x; h[1] = (_Float16)aregf[j].y;
                h[2] = (_Float16)aregf[j].z; h[3] = (_Float16)aregf[j].w;
                *(half4_t*)&Asl[ar][ak + 16 * j] = h;
            }
        } else {
            #pragma unroll
            for (int j = 0; j < 4; j++)
                *(half4_t*)&Asl[ar][ak + 16 * j] = aregh[j];
        }
        half8_t h0, h1;
        #pragma unroll
        for (int i = 0; i < 8; i++) { h0[i] = (_Float16)breg[i]; h1[i] = (_Float16)breg[i + 8]; }
        *(half8_t*)&Bsl[bn][bk]     = h0;
        *(half8_t*)&Bsl[bn][bk + 8] = h1;
    };

    do_load(0);
    for (int t0 = 0; t0 < D_DIM; t0 += BK) {
        __syncthreads();          // all waves done reading previous tile
        do_write();
        if (t0 + BK < D_DIM) do_load(t0 + BK);   // in flight across barrier + MFMA phase
        __syncthreads();          // tile ready
        #pragma unroll
        for (int kc = 0; kc < 4; kc++) {
            half8_t a = *(const half8_t*)&Asl[wr + fr][kc * 16 + kg * 8];
            half8_t b = *(const half8_t*)&Bsl[wc + fr][kc * 16 + kg * 8];
            acc = __builtin_amdgcn_mfma_f32_32x32x16_f16(a, b, acc, 0, 0, 0);
        }
    }

    // epilogue: C layout for 32x32: col = lane&31, row = (r&3) + 8*(r>>2) + 4*(lane>>5)
    const int gcol = ct * NT + wc + fr;
    const float bb = bias[(size_t)e * D_DIM + gcol];
    #pragma unroll
    for (int r = 0; r < 16; r++) {
        int row_l = wr + (r & 3) + 8 * (r >> 2) + 4 * kg;
        int grow = rt * MT + row_l;
        if (grow < n) {
            float v = acc[r] + bb;
            if constexpr (WHICH == 1)
                Hout[(size_t)(base + grow) * D_DIM + gcol] = (_Float16)tanhf(v);
            else
                Sout[(size_t)(base + grow) * D_DIM + gcol] = v;
        }
    }
}

// ---------------- softmax + combine: one block per output row ----------------
__global__ __launch_bounds__(256) void combine_kernel(
    const float* __restrict__ S, const float* __restrict__ x,
    const int* __restrict__ offs, const int* __restrict__ slot_e,
    const int* __restrict__ slot_p, const float* __restrict__ gsel,
    float* __restrict__ y)
{
    const int b = blockIdx.x, t = threadIdx.x;
    const int e0 = slot_e[2 * b], e1 = slot_e[2 * b + 1];
    const float* S0 = S + (size_t)(offs[e0] + slot_p[2 * b]) * D_DIM;
    const float* S1 = S + (size_t)(offs[e1] + slot_p[2 * b + 1]) * D_DIM;
    const float g0 = gsel[2 * b], g1 = gsel[2 * b + 1];
    __shared__ float sm[2][4];
    const int wid = t >> 6, lane = t & 63;

    float m0 = -3.0e38f, m1 = -3.0e38f;
    for (int d = t; d < D_DIM; d += 256) {
        m0 = fmaxf(m0, S0[d]);
        m1 = fmaxf(m1, S1[d]);
    }
    #pragma unroll
    for (int off = 32; off >= 1; off >>= 1) {
        m0 = fmaxf(m0, __shfl_down(m0, off));
        m1 = fmaxf(m1, __shfl_down(m1, off));
    }
    if (lane == 0) { sm[0][wid] = m0; sm[1][wid] = m1; }
    __syncthreads();
    m0 = fmaxf(fmaxf(sm[0][0], sm[0][1]), fmaxf(sm[0][2], sm[0][3]));
    m1 = fmaxf(fmaxf(sm[1][0], sm[1][1]), fmaxf(sm[1][2], sm[1][3]));
    __syncthreads();

    float s0 = 0.f, s1 = 0.f;
    for (int d = t; d < D_DIM; d += 256) {
        s0 += expf(S0[d] - m0);
        s1 += expf(S1[d] - m1);
    }
    #pragma unroll
    for (int off = 32; off >= 1; off >>= 1) {
        s0 += __shfl_down(s0, off);
        s1 += __shfl_down(s1, off);
    }
    if (lane == 0) { sm[0][wid] = s0; sm[1][wid] = s1; }
    __syncthreads();
    s0 = sm[0][0] + sm[0][1] + sm[0][2] + sm[0][3];
    s1 = sm[1][0] + sm[1][1] + sm[1][2] + sm[1][3];
    const float inv0 = 1.f / s0, inv1 = 1.f / s1;

    for (int d = t; d < D_DIM; d += 256) {
        float a0 = expf(S0[d] - m0) * inv0;
        float a1 = expf(S1[d] - m1) * inv1;
        float xv = x[(size_t)b * D_DIM + d];
        float c = g0 * expf(a0 * xv) + g1 * expf(a1 * xv);
        if (c == 0.f) c = 2.220446049250313e-16f;
        y[(size_t)b * D_DIM + d] = logf(c);
    }
}

extern "C" void kernel_launch(void* const* d_in, const int* in_sizes, int n_in,
                              void* d_out, int out_size, void* d_ws, size_t ws_size,
                              hipStream_t stream) {
    const float* x       = (const float*)d_in[0];
    const float* noise   = (const float*)d_in[1];
    const float* w_gate  = (const float*)d_in[2];
    const float* w_noise = (const float*)d_in[3];
    const float* W1      = (const float*)d_in[4];
    const float* b1      = (const float*)d_in[5];
    const float* W2      = (const float*)d_in[6];
    const float* b2      = (const float*)d_in[7];
    float* out = (float*)d_out;
    char* ws = (char*)d_ws;
    if (ws_size < (size_t)WS_NEEDED) return;

    int*      cnt    = (int*)(ws + O_CNT);
    int*      offs   = (int*)(ws + O_OFFS);
    int*      rows   = (int*)(ws + O_ROWS);
    int*      slot_e = (int*)(ws + O_SLOTE);
    int*      slot_p = (int*)(ws + O_SLOTP);
    float*    gsel   = (float*)(ws + O_GSEL);
    float*    gates  = (float*)(ws + O_GATES);
    float*    prob   = (float*)(ws + O_PROB);
    _Float16* H      = (_Float16*)(ws + O_H);
    float*    S      = (float*)(ws + O_S);

    hipMemsetAsync(cnt, 0, 8 * sizeof(int), stream);
    gate_kernel<<<512, 256, 0, stream>>>(x, noise, w_gate, w_noise,
                                         gates, prob, gsel, cnt, rows, slot_e, slot_p);
    loss_kernel<<<1, 256, 0, stream>>>(gates, prob, cnt, offs, out + (size_t)B_ROWS * D_DIM);
    expert_gemm_mfma<1><<<dim3(8, 32, 8), 256, 0, stream>>>(x, nullptr, W1, b1, H, nullptr, cnt, offs, rows);
    expert_gemm_mfma<2><<<dim3(8, 32, 8), 256, 0, stream>>>(nullptr, H, W2, b2, nullptr, S, cnt, offs, rows);
    combine_kernel<<<512, 256, 0, stream>>>(S, x, offs, slot_e, slot_p, gsel, out);
}